// Round 8
// baseline (187.855 us; speedup 1.0000x reference)
//
#include <hip/hip_runtime.h>
#include <hip/hip_bf16.h>

// Problem: B=2048, DIM=2048, SKETCH=256, SIZE=131072
//   sx = normalize_rows(x @ R); out = 1 - max_row(sx @ buffer^T)

#define BROWS 2048
#define DIM   2048
#define SKDIM 256
#define NBUF  131072

// gemm_sim v9: A-in-registers + 32x32x16 MFMA. 512 blocks (16 m x 32 nc),
// 256 thr (4 waves, 2x2, wave tile 64x64 = 2x2 frags of 32x32). K=256 in
// VGPRs (areg[2][16] = 128 regs). B streams via 4 LDS slots x 16KB,
// stage g+3 at window g, counted vmcnt(8), ONE barrier/window.
#define NGROUPS 32            // n-chunks (4096 cols each)
#define NT_PER  32            // 128-col n-tiles per block

typedef __attribute__((ext_vector_type(4))) float f32x4;
typedef __attribute__((ext_vector_type(16))) float f32x16;
typedef __attribute__((ext_vector_type(8))) short bf16x8;
typedef __attribute__((ext_vector_type(4))) short bf16x4;

static __device__ inline unsigned short f2bf(float f) {
  unsigned u = __float_as_uint(f);
  unsigned r = u + 0x7FFFu + ((u >> 16) & 1u);  // round-to-nearest-even
  return (unsigned short)(r >> 16);
}

static __device__ inline bf16x8 cvt8(const float* __restrict__ p) {
  f32x4 a = *(const f32x4*)p;
  f32x4 b = *(const f32x4*)(p + 4);
  bf16x8 r;
  r[0] = (short)f2bf(a[0]); r[1] = (short)f2bf(a[1]);
  r[2] = (short)f2bf(a[2]); r[3] = (short)f2bf(a[3]);
  r[4] = (short)f2bf(b[0]); r[5] = (short)f2bf(b[1]);
  r[6] = (short)f2bf(b[2]); r[7] = (short)f2bf(b[3]);
  return r;
}

// K0: RT_bf[n][k] = bf16(R[k][n])   (256 x 2048)
__global__ void transpose_R(const float* __restrict__ R, unsigned short* __restrict__ rt) {
  int idx = blockIdx.x * 256 + threadIdx.x;
  int k = idx >> 8, n = idx & 255;
  rt[n * DIM + k] = f2bf(R[idx]);
}

// K1+K2 fused: blocks 0..31 = gemm_sketch; blocks 32..2079 = conv_buf.
__launch_bounds__(256)
__global__ void sketch_conv(const float* __restrict__ x, const unsigned short* __restrict__ rt,
                            unsigned short* __restrict__ sx,
                            const float* __restrict__ bufin, unsigned short* __restrict__ outb) {
  __shared__ unsigned short As[64][72];
  __shared__ unsigned short Bs[256][72];
  __shared__ float ssum[4][64];

  if (blockIdx.x >= 32) {
    // ---- conv path ----
    const int nvec = (NBUF * SKDIM) / 4;
    int stride = 2048 * 256;
    for (int i = (blockIdx.x - 32) * 256 + threadIdx.x; i < nvec; i += stride) {
      f32x4 v = ((const f32x4*)bufin)[i];
      bf16x4 r;
      r[0] = (short)f2bf(v[0]); r[1] = (short)f2bf(v[1]);
      r[2] = (short)f2bf(v[2]); r[3] = (short)f2bf(v[3]);
      ((bf16x4*)outb)[i] = r;
    }
    return;
  }

  // ---- sketch path (validated R0-R6) ----
  const int m0 = blockIdx.x * 64;
  const int tid = threadIdx.x;
  const int w = tid >> 6, l = tid & 63;
  const int lr = l & 15, q = l >> 4;

  f32x4 acc[4][4] = {};

  for (int k0 = 0; k0 < DIM; k0 += 64) {
    #pragma unroll
    for (int i = 0; i < 2; ++i) {
      int v = tid + i * 256;
      int r = v >> 3, vc = v & 7;
      *(bf16x8*)&As[r][vc * 8] = cvt8(x + (size_t)(m0 + r) * DIM + k0 + vc * 8);
    }
    #pragma unroll
    for (int i = 0; i < 8; ++i) {
      int v = tid + i * 256;
      int r = v >> 3, vc = v & 7;
      *(bf16x8*)&Bs[r][vc * 8] = *(const bf16x8*)(rt + (size_t)r * DIM + k0 + vc * 8);
    }
    __syncthreads();
    #pragma unroll
    for (int ks = 0; ks < 2; ++ks) {
      int kk = ks * 32 + q * 8;
      bf16x8 a[4], b[4];
      #pragma unroll
      for (int mi = 0; mi < 4; ++mi) a[mi] = *(bf16x8*)&As[mi * 16 + lr][kk];
      #pragma unroll
      for (int ni = 0; ni < 4; ++ni) b[ni] = *(bf16x8*)&Bs[w * 64 + ni * 16 + lr][kk];
      #pragma unroll
      for (int mi = 0; mi < 4; ++mi)
        #pragma unroll
        for (int ni = 0; ni < 4; ++ni)
          acc[mi][ni] = __builtin_amdgcn_mfma_f32_16x16x32_bf16(a[mi], b[ni], acc[mi][ni], 0, 0, 0);
    }
    __syncthreads();
  }

  float ps[4][4];
  #pragma unroll
  for (int mi = 0; mi < 4; ++mi)
    #pragma unroll
    for (int rg = 0; rg < 4; ++rg) {
      float s = acc[mi][0][rg] * acc[mi][0][rg] + acc[mi][1][rg] * acc[mi][1][rg]
              + acc[mi][2][rg] * acc[mi][2][rg] + acc[mi][3][rg] * acc[mi][3][rg];
      #pragma unroll
      for (int m = 1; m < 16; m <<= 1) s += __shfl_xor(s, m);
      ps[mi][rg] = s;
    }
  if (lr == 0) {
    #pragma unroll
    for (int mi = 0; mi < 4; ++mi)
      #pragma unroll
      for (int rg = 0; rg < 4; ++rg)
        ssum[w][mi * 16 + q * 4 + rg] = ps[mi][rg];
  }
  __syncthreads();

  #pragma unroll
  for (int mi = 0; mi < 4; ++mi)
    #pragma unroll
    for (int rg = 0; rg < 4; ++rg) {
      int r = mi * 16 + q * 4 + rg;
      float tot = ssum[0][r] + ssum[1][r] + ssum[2][r] + ssum[3][r];
      float inv = 1.0f / fmaxf(sqrtf(tot), 1e-12f);
      #pragma unroll
      for (int ni = 0; ni < 4; ++ni) {
        float val = acc[mi][ni][rg] * inv;
        sx[(size_t)(m0 + r) * SKDIM + w * 64 + ni * 16 + lr] = f2bf(val);
      }
    }
}

// K3 v9: A-in-regs, 32x32x16 MFMA.
// areg[mi][kc]: lane l holds A[row = m0+wr*64+mi*32+(l&31)][k = kc*16+(l>>5)*8 ..+8)
// LDS B: 4 slots x [128 cols][64 k] bf16 (16KB, row stride 128B = 8 x 16B
// slots). Staging identical to v8 (linear dest, source col-slot pre-swizzled
// by (row>>1)&7). Read (32x32): lane l, kslice t, frag ni: row =
// wc*64+ni*32+(l&31), chunk = (t<<1)|(l>>5), slot = chunk ^ (((l&31)>>1)&7).
// Per 16-lane phase: chunk fixed, key = r'>>1 covers 8 slots x 2 lanes ->
// conflict-free (same model that measured 0 conflicts in v8).
// MFMA per window: 4 kslices x 2 mi x 2 ni = 16 x 32x32x16 (t-outer: dep
// distance 4). C/D: col=lane&31, row=(reg&3)+8*(reg>>2)+4*(lane>>5) [m74/m101].
__launch_bounds__(256, 2)
__global__ void gemm_sim(const unsigned short* __restrict__ sx,
                         const unsigned short* __restrict__ bufb,
                         float* __restrict__ partial) {
  __shared__ __align__(16) char lb[65536];

  // XCD-chunked swizzle (512 blocks = 8 XCDs x 64), m-fastest inner.
  const int gid = blockIdx.x;
  const int logical = (gid & 7) * 64 + (gid >> 3);
  const int mt = logical & 15;       // 0..15 m-tile (128 rows)
  const int nc = logical >> 4;       // 0..31 n-chunk (4096 cols)
  const int m0 = mt * 128;
  const int ncbase = nc * (NT_PER * 128);

  const int tid = threadIdx.x;
  const int w = tid >> 6, l = tid & 63;
  const int wr = w >> 1, wc = w & 1;        // wave grid 2 x 2
  const int c31 = l & 31, hi = l >> 5;

  // staging constants (unchanged from v8): LDS dest linear, source
  // col-slot pre-swizzled by (row>>1)&7 where row = tid>>3 (+32j).
  const int scol = ((tid & 7) ^ ((tid >> 4) & 7)) * 8;   // elements

  // read constants: base = row-in-tile; per-kslice swizzled byte offsets
  const char* pbase;
  int offt[4];
  {
    const int key = (c31 >> 1) & 7;
    #pragma unroll
    for (int t = 0; t < 4; ++t) offt[t] = ((((t << 1) | hi) ^ key) << 4);
  }

  // ---- A resident in registers ----
  bf16x8 areg[2][16];
  {
    const unsigned short* abase = sx + (size_t)(m0 + wr * 64 + c31) * SKDIM + hi * 8;
    #pragma unroll
    for (int mi = 0; mi < 2; ++mi)
      #pragma unroll
      for (int kc = 0; kc < 16; ++kc)
        areg[mi][kc] = *(const bf16x8*)(abase + mi * 32 * SKDIM + kc * 16);
  }

  f32x16 acc[2][2] = {};
  float rm[2][16];
  #pragma unroll
  for (int mi = 0; mi < 2; ++mi)
    #pragma unroll
    for (int r = 0; r < 16; ++r) rm[mi][r] = -3.0e38f;

#define STAGE(srcb, kpart, slot_) do {                                         \
    const unsigned short* s0_ = (srcb) + (kpart) * 64;                         \
    char* dst_ = lb + (slot_) * 16384 + tid * 16;                              \
    _Pragma("unroll")                                                          \
    for (int j_ = 0; j_ < 4; ++j_) {                                           \
      __builtin_amdgcn_global_load_lds(                                        \
          (const __attribute__((address_space(1))) unsigned int*)(s0_ + j_ * 32 * SKDIM), \
          (__attribute__((address_space(3))) unsigned int*)(dst_ + j_ * 4096), \
          16, 0, 0);                                                           \
    }                                                                          \
  } while (0)

#define COMPUTE(ks)                                                            \
    {                                                                          \
      bf16x8 bf[4][2];                                                         \
      _Pragma("unroll")                                                        \
      for (int t = 0; t < 4; ++t) {                                            \
        bf[t][0] = *(const bf16x8*)(pbase + offt[t] + ((ks) * 16384));         \
        bf[t][1] = *(const bf16x8*)(pbase + offt[t] + ((ks) * 16384 + 4096));  \
      }                                                                        \
      __builtin_amdgcn_s_setprio(1);                                           \
      _Pragma("unroll")                                                        \
      for (int t = 0; t < 4; ++t) {                                            \
        acc[0][0] = __builtin_amdgcn_mfma_f32_32x32x16_bf16(areg[0][(ks) * 4 + t], bf[t][0], acc[0][0], 0, 0, 0); \
        acc[0][1] = __builtin_amdgcn_mfma_f32_32x32x16_bf16(areg[0][(ks) * 4 + t], bf[t][1], acc[0][1], 0, 0, 0); \
        acc[1][0] = __builtin_amdgcn_mfma_f32_32x32x16_bf16(areg[1][(ks) * 4 + t], bf[t][0], acc[1][0], 0, 0, 0); \
        acc[1][1] = __builtin_amdgcn_mfma_f32_32x32x16_bf16(areg[1][(ks) * 4 + t], bf[t][1], acc[1][1], 0, 0, 0); \
      }                                                                        \
      __builtin_amdgcn_s_setprio(0);                                           \
    }

  pbase = lb + (wc * 64 + c31) * 128;

  const unsigned short* bsrc = bufb + (size_t)(ncbase + (tid >> 3)) * SKDIM + scol;

  // prologue: stage windows 0,1,2 (slots 0,1,2)
  STAGE(bsrc, 0, 0);
  STAGE(bsrc, 1, 1);
  STAGE(bsrc, 2, 2);

  for (int nt = 0; nt < NT_PER; ++nt) {
    const unsigned short* bcur = bsrc;     // base for current nt
    bsrc += 128 * SKDIM;                   // base for nt+1
    const bool more = (nt < NT_PER - 1);

    // ---- window ks=0 ----
    asm volatile("s_waitcnt vmcnt(8)" ::: "memory");
    asm volatile("s_barrier" ::: "memory");
    STAGE(bcur, 3, 3);
    COMPUTE(0)

    // ---- window ks=1 ----
    asm volatile("s_waitcnt vmcnt(8)" ::: "memory");
    asm volatile("s_barrier" ::: "memory");
    if (more) STAGE(bsrc, 0, 0);
    COMPUTE(1)

    // ---- window ks=2 ----
    if (more) { asm volatile("s_waitcnt vmcnt(8)" ::: "memory"); }
    else      { asm volatile("s_waitcnt vmcnt(4)" ::: "memory"); }
    asm volatile("s_barrier" ::: "memory");
    if (more) STAGE(bsrc, 1, 1);
    COMPUTE(2)

    // ---- window ks=3 ----
    if (more) { asm volatile("s_waitcnt vmcnt(8)" ::: "memory"); }
    else      { asm volatile("s_waitcnt vmcnt(0)" ::: "memory"); }
    asm volatile("s_barrier" ::: "memory");
    if (more) STAGE(bsrc, 2, 2);
    COMPUTE(3)

    // n-tile complete: fold row-max, reset acc
    #pragma unroll
    for (int mi = 0; mi < 2; ++mi)
      #pragma unroll
      for (int r = 0; r < 16; ++r) {
        rm[mi][r] = fmaxf(rm[mi][r], fmaxf(acc[mi][0][r], acc[mi][1][r]));
        acc[mi][0][r] = 0.0f;
        acc[mi][1][r] = 0.0f;
      }
  }
#undef STAGE
#undef COMPUTE

  // epilogue: reduce over the 32 cols held across the 32-lane group
  #pragma unroll
  for (int mi = 0; mi < 2; ++mi)
    #pragma unroll
    for (int r = 0; r < 16; ++r) {
      float v = rm[mi][r];
      v = fmaxf(v, __shfl_xor(v, 1));
      v = fmaxf(v, __shfl_xor(v, 2));
      v = fmaxf(v, __shfl_xor(v, 4));
      v = fmaxf(v, __shfl_xor(v, 8));
      v = fmaxf(v, __shfl_xor(v, 16));
      rm[mi][r] = v;
    }

  float* rmaxs = (float*)lb;   // reuse staging LDS: [2 wc][128 rows]
  __syncthreads();
  if (c31 == 0) {
    #pragma unroll
    for (int mi = 0; mi < 2; ++mi)
      #pragma unroll
      for (int r = 0; r < 16; ++r) {
        int row = wr * 64 + mi * 32 + (r & 3) + 8 * (r >> 2) + 4 * hi;
        rmaxs[wc * 128 + row] = rm[mi][r];
      }
  }
  __syncthreads();
  if (tid < 128) {
    float v = fmaxf(rmaxs[tid], rmaxs[128 + tid]);
    partial[(size_t)(m0 + tid) * NGROUPS + nc] = v;
  }
}

// K4: out[r] = 1 - max over 32 partials. 2 rows per 64-thread block.
__global__ void reduce_max(const float* __restrict__ partial, float* __restrict__ out) {
  const int r = blockIdx.x * 2 + (threadIdx.x >> 5);
  const int c = threadIdx.x & 31;
  float m = partial[(size_t)r * NGROUPS + c];
  #pragma unroll
  for (int s = 1; s < 32; s <<= 1) m = fmaxf(m, __shfl_xor(m, s));
  if (c == 0) out[r] = 1.0f - m;
}

extern "C" void kernel_launch(void* const* d_in, const int* in_sizes, int n_in,
                              void* d_out, int out_size, void* d_ws, size_t ws_size,
                              hipStream_t stream) {
  const float* x   = (const float*)d_in[0];   // [2048, 2048]
  const float* R   = (const float*)d_in[1];   // [2048, 256]
  const float* buf = (const float*)d_in[2];   // [131072, 256]
  float* out = (float*)d_out;                  // [2048]

  char* ws = (char*)d_ws;
  // ws layout: rt 1MB | buf_bf 64MB | sx_bf 1MB | partial 256KB
  unsigned short* rt   = (unsigned short*)(ws);
  unsigned short* bufb = (unsigned short*)(ws + (1ull << 20));
  unsigned short* sxb  = (unsigned short*)(ws + (1ull << 20) + (64ull << 20));
  float*          part = (float*)         (ws + (1ull << 20) + (64ull << 20) + (1ull << 20));

  transpose_R<<<dim3((DIM * SKDIM) / 256), dim3(256), 0, stream>>>(R, rt);
  sketch_conv<<<dim3(2080), dim3(256), 0, stream>>>(x, rt, sxb, buf, bufb);
  gemm_sim<<<dim3(512), dim3(256), 0, stream>>>(sxb, bufb, part);
  reduce_max<<<dim3(BROWS / 2), dim3(64), 0, stream>>>(part, out);
}

// Round 9
// 170.175 us; speedup vs baseline: 1.1039x; 1.1039x over previous
//
#include <hip/hip_runtime.h>
#include <hip/hip_bf16.h>

// Problem: B=2048, DIM=2048, SKETCH=256, SIZE=131072
//   sx = normalize_rows(x @ R); out = 1 - max_row(sx @ buffer^T)

#define BROWS 2048
#define DIM   2048
#define SKDIM 256
#define NBUF  131072

// gemm_sim v10: v8 structure (16x16x32, A-in-regs, 4 LDS slots, counted
// vmcnt, one barrier/window) + cross-window register prefetch of chunk-0
// B-frags. Head vmcnt(4) confirms slot g+1 at window g, so windows start
// with MFMAs on prefetched regs — no post-barrier ds_read storm.
#define NGROUPS 32            // n-chunks (4096 cols each)
#define NT_PER  32            // 128-col n-tiles per block

typedef __attribute__((ext_vector_type(4))) float f32x4;
typedef __attribute__((ext_vector_type(8))) short bf16x8;
typedef __attribute__((ext_vector_type(4))) short bf16x4;

static __device__ inline unsigned short f2bf(float f) {
  unsigned u = __float_as_uint(f);
  unsigned r = u + 0x7FFFu + ((u >> 16) & 1u);  // round-to-nearest-even
  return (unsigned short)(r >> 16);
}

static __device__ inline bf16x8 cvt8(const float* __restrict__ p) {
  f32x4 a = *(const f32x4*)p;
  f32x4 b = *(const f32x4*)(p + 4);
  bf16x8 r;
  r[0] = (short)f2bf(a[0]); r[1] = (short)f2bf(a[1]);
  r[2] = (short)f2bf(a[2]); r[3] = (short)f2bf(a[3]);
  r[4] = (short)f2bf(b[0]); r[5] = (short)f2bf(b[1]);
  r[6] = (short)f2bf(b[2]); r[7] = (short)f2bf(b[3]);
  return r;
}

// K0: RT_bf[n][k] = bf16(R[k][n])   (256 x 2048)
__global__ void transpose_R(const float* __restrict__ R, unsigned short* __restrict__ rt) {
  int idx = blockIdx.x * 256 + threadIdx.x;
  int k = idx >> 8, n = idx & 255;
  rt[n * DIM + k] = f2bf(R[idx]);
}

// K1+K2 fused: blocks 0..31 = gemm_sketch; blocks 32..2079 = conv_buf.
__launch_bounds__(256)
__global__ void sketch_conv(const float* __restrict__ x, const unsigned short* __restrict__ rt,
                            unsigned short* __restrict__ sx,
                            const float* __restrict__ bufin, unsigned short* __restrict__ outb) {
  __shared__ unsigned short As[64][72];
  __shared__ unsigned short Bs[256][72];
  __shared__ float ssum[4][64];

  if (blockIdx.x >= 32) {
    // ---- conv path ----
    const int nvec = (NBUF * SKDIM) / 4;
    int stride = 2048 * 256;
    for (int i = (blockIdx.x - 32) * 256 + threadIdx.x; i < nvec; i += stride) {
      f32x4 v = ((const f32x4*)bufin)[i];
      bf16x4 r;
      r[0] = (short)f2bf(v[0]); r[1] = (short)f2bf(v[1]);
      r[2] = (short)f2bf(v[2]); r[3] = (short)f2bf(v[3]);
      ((bf16x4*)outb)[i] = r;
    }
    return;
  }

  // ---- sketch path (validated R0-R7) ----
  const int m0 = blockIdx.x * 64;
  const int tid = threadIdx.x;
  const int w = tid >> 6, l = tid & 63;
  const int lr = l & 15, q = l >> 4;

  f32x4 acc[4][4] = {};

  for (int k0 = 0; k0 < DIM; k0 += 64) {
    #pragma unroll
    for (int i = 0; i < 2; ++i) {
      int v = tid + i * 256;
      int r = v >> 3, vc = v & 7;
      *(bf16x8*)&As[r][vc * 8] = cvt8(x + (size_t)(m0 + r) * DIM + k0 + vc * 8);
    }
    #pragma unroll
    for (int i = 0; i < 8; ++i) {
      int v = tid + i * 256;
      int r = v >> 3, vc = v & 7;
      *(bf16x8*)&Bs[r][vc * 8] = *(const bf16x8*)(rt + (size_t)r * DIM + k0 + vc * 8);
    }
    __syncthreads();
    #pragma unroll
    for (int ks = 0; ks < 2; ++ks) {
      int kk = ks * 32 + q * 8;
      bf16x8 a[4], b[4];
      #pragma unroll
      for (int mi = 0; mi < 4; ++mi) a[mi] = *(bf16x8*)&As[mi * 16 + lr][kk];
      #pragma unroll
      for (int ni = 0; ni < 4; ++ni) b[ni] = *(bf16x8*)&Bs[w * 64 + ni * 16 + lr][kk];
      #pragma unroll
      for (int mi = 0; mi < 4; ++mi)
        #pragma unroll
        for (int ni = 0; ni < 4; ++ni)
          acc[mi][ni] = __builtin_amdgcn_mfma_f32_16x16x32_bf16(a[mi], b[ni], acc[mi][ni], 0, 0, 0);
    }
    __syncthreads();
  }

  float ps[4][4];
  #pragma unroll
  for (int mi = 0; mi < 4; ++mi)
    #pragma unroll
    for (int rg = 0; rg < 4; ++rg) {
      float s = acc[mi][0][rg] * acc[mi][0][rg] + acc[mi][1][rg] * acc[mi][1][rg]
              + acc[mi][2][rg] * acc[mi][2][rg] + acc[mi][3][rg] * acc[mi][3][rg];
      #pragma unroll
      for (int m = 1; m < 16; m <<= 1) s += __shfl_xor(s, m);
      ps[mi][rg] = s;
    }
  if (lr == 0) {
    #pragma unroll
    for (int mi = 0; mi < 4; ++mi)
      #pragma unroll
      for (int rg = 0; rg < 4; ++rg)
        ssum[w][mi * 16 + q * 4 + rg] = ps[mi][rg];
  }
  __syncthreads();

  #pragma unroll
  for (int mi = 0; mi < 4; ++mi)
    #pragma unroll
    for (int rg = 0; rg < 4; ++rg) {
      int r = mi * 16 + q * 4 + rg;
      float tot = ssum[0][r] + ssum[1][r] + ssum[2][r] + ssum[3][r];
      float inv = 1.0f / fmaxf(sqrtf(tot), 1e-12f);
      #pragma unroll
      for (int ni = 0; ni < 4; ++ni) {
        float val = acc[mi][ni][rg] * inv;
        sx[(size_t)(m0 + r) * SKDIM + w * 64 + ni * 16 + lr] = f2bf(val);
      }
    }
}

// K3 v10: A-in-regs, 16x16x32, 4 LDS slots, cross-window B-prefetch.
// Per window g (slot = ks = g&3, compile-time):
//   vmcnt(4) [confirms slot g+1]; s_barrier; STAGE(g+3);
//   ds_read b1 <- slot g chunk1; 16 MFMA chunk0 (bfn regs, prefetched);
//   ds_read bfn <- slot g+1 chunk0; 16 MFMA chunk1 (b1); fold at ks==3.
// WAR audit: reads of slot s are lgkm-consumed by MFMAs before barrier(s+1);
// STAGE(s+4) (overwriting slot s&3) issues after barrier(s+1). Reads of slot
// g+1 issued in window g complete before its use-window g+1 ends, and slot
// g+1 is not overwritten until STAGE(g+5) (window g+2). Safe.
__launch_bounds__(256, 2)
__global__ void gemm_sim(const unsigned short* __restrict__ sx,
                         const unsigned short* __restrict__ bufb,
                         float* __restrict__ partial) {
  __shared__ __align__(16) char lb[65536];

  // XCD-chunked swizzle (512 blocks = 8 XCDs x 64), m-fastest inner.
  const int gid = blockIdx.x;
  const int logical = (gid & 7) * 64 + (gid >> 3);
  const int mt = logical & 15;       // 0..15 m-tile (128 rows)
  const int nc = logical >> 4;       // 0..31 n-chunk (4096 cols)
  const int m0 = mt * 128;
  const int ncbase = nc * (NT_PER * 128);

  const int tid = threadIdx.x;
  const int w = tid >> 6, l = tid & 63;
  const int wr = w >> 1, wc = w & 1;        // wave grid 2 x 2
  const int lr = l & 15, q = l >> 4;

  // staging: LDS linear dest (row = tid>>3 (+32j), 16B slot tid&7);
  // global source col-slot pre-swizzled by (row>>1)&7 = (tid>>4)&7.
  const int scol = ((tid & 7) ^ ((tid >> 4) & 7)) * 8;   // elements
  // read swizzle: chunk-c slot = (c*4+q) ^ ((lr>>1)&7)
  const int off0 = ((q ^ ((lr >> 1) & 7)) << 4);
  const int off1 = off0 ^ 64;
  const int rowoff = (wc * 64 + lr) * 128;

  // ---- A resident in registers: rows m0+wr*64+mi*16+lr, k = kc*32+q*8
  bf16x8 areg[4][8];
  {
    const unsigned short* abase = sx + (size_t)(m0 + wr * 64 + lr) * SKDIM + q * 8;
    #pragma unroll
    for (int mi = 0; mi < 4; ++mi)
      #pragma unroll
      for (int kc = 0; kc < 8; ++kc)
        areg[mi][kc] = *(const bf16x8*)(abase + mi * 16 * SKDIM + kc * 32);
  }

  f32x4 acc[4][4] = {};
  float rm[4][4];
  #pragma unroll
  for (int mi = 0; mi < 4; ++mi)
    #pragma unroll
    for (int rg = 0; rg < 4; ++rg) rm[mi][rg] = -3.0e38f;

  bf16x8 bfn[4];   // prefetched chunk-0 B frags for the upcoming window

#define STAGE(srcb, kpart, slot_) do {                                         \
    const unsigned short* s0_ = (srcb) + (kpart) * 64;                         \
    char* dst_ = lb + (slot_) * 16384 + tid * 16;                              \
    _Pragma("unroll")                                                          \
    for (int j_ = 0; j_ < 4; ++j_) {                                           \
      __builtin_amdgcn_global_load_lds(                                        \
          (const __attribute__((address_space(1))) unsigned int*)(s0_ + j_ * 32 * SKDIM), \
          (__attribute__((address_space(3))) unsigned int*)(dst_ + j_ * 4096), \
          16, 0, 0);                                                           \
    }                                                                          \
  } while (0)

#define RDNEXT(slotN)                                                          \
    _Pragma("unroll")                                                          \
    for (int ni = 0; ni < 4; ++ni)                                             \
      bfn[ni] = *(const bf16x8*)(lb + (slotN) * 16384 + rowoff + ni * 2048 + off0);

#define WINDOW(ks, VM, STAGE_STMT, RDNEXT_STMT) do {                           \
    asm volatile("s_waitcnt vmcnt(" #VM ")" ::: "memory");                     \
    asm volatile("s_barrier" ::: "memory");                                    \
    STAGE_STMT;                                                                \
    bf16x8 b1[4];                                                              \
    _Pragma("unroll")                                                          \
    for (int ni = 0; ni < 4; ++ni)                                             \
      b1[ni] = *(const bf16x8*)(lb + (ks) * 16384 + rowoff + ni * 2048 + off1); \
    __builtin_amdgcn_s_setprio(1);                                             \
    _Pragma("unroll")                                                          \
    for (int mi = 0; mi < 4; ++mi)                                             \
      _Pragma("unroll")                                                        \
      for (int ni = 0; ni < 4; ++ni)                                           \
        acc[mi][ni] = __builtin_amdgcn_mfma_f32_16x16x32_bf16(areg[mi][(ks) * 2], bfn[ni], acc[mi][ni], 0, 0, 0); \
    __builtin_amdgcn_s_setprio(0);                                             \
    RDNEXT_STMT;                                                               \
    __builtin_amdgcn_s_setprio(1);                                             \
    _Pragma("unroll")                                                          \
    for (int mi = 0; mi < 4; ++mi)                                             \
      _Pragma("unroll")                                                        \
      for (int ni = 0; ni < 4; ++ni)                                           \
        acc[mi][ni] = __builtin_amdgcn_mfma_f32_16x16x32_bf16(areg[mi][(ks) * 2 + 1], b1[ni], acc[mi][ni], 0, 0, 0); \
    __builtin_amdgcn_s_setprio(0);                                             \
  } while (0)

#define FOLD do {                                                              \
    _Pragma("unroll")                                                          \
    for (int mi = 0; mi < 4; ++mi)                                             \
      _Pragma("unroll")                                                        \
      for (int rg = 0; rg < 4; ++rg) {                                         \
        float v = fmaxf(fmaxf(acc[mi][0][rg], acc[mi][1][rg]),                 \
                        fmaxf(acc[mi][2][rg], acc[mi][3][rg]));                \
        rm[mi][rg] = fmaxf(rm[mi][rg], v);                                     \
        _Pragma("unroll")                                                      \
        for (int ni = 0; ni < 4; ++ni) acc[mi][ni][rg] = 0.0f;                 \
      }                                                                        \
  } while (0)

  const unsigned short* bsrc = bufb + (size_t)(ncbase + (tid >> 3)) * SKDIM + scol;

  // prologue: stage slots 0,1,2; confirm slot 0; prefetch its chunk0
  STAGE(bsrc, 0, 0);
  STAGE(bsrc, 1, 1);
  STAGE(bsrc, 2, 2);
  asm volatile("s_waitcnt vmcnt(8)" ::: "memory");
  asm volatile("s_barrier" ::: "memory");
  RDNEXT(0);

  for (int nt = 0; nt < NT_PER - 1; ++nt) {
    const unsigned short* bcur = bsrc;
    bsrc += 128 * SKDIM;
    WINDOW(0, 4, STAGE(bcur, 3, 3), RDNEXT(1));
    WINDOW(1, 4, STAGE(bsrc, 0, 0), RDNEXT(2));
    WINDOW(2, 4, STAGE(bsrc, 1, 1), RDNEXT(3));
    WINDOW(3, 4, STAGE(bsrc, 2, 2), RDNEXT(0));
    FOLD;
  }
  {  // tail n-tile (nt = NT_PER-1): no next-tile stages; drain counts
    const unsigned short* bcur = bsrc;
    WINDOW(0, 4, STAGE(bcur, 3, 3), RDNEXT(1));
    WINDOW(1, 4, (void)0, RDNEXT(2));
    WINDOW(2, 0, (void)0, RDNEXT(3));
    WINDOW(3, 0, (void)0, (void)0);
    FOLD;
  }
#undef STAGE
#undef RDNEXT
#undef WINDOW
#undef FOLD

  // epilogue: reduce over the 16 cols held across lr lanes
  #pragma unroll
  for (int mi = 0; mi < 4; ++mi)
    #pragma unroll
    for (int rg = 0; rg < 4; ++rg) {
      float v = rm[mi][rg];
      v = fmaxf(v, __shfl_xor(v, 1));
      v = fmaxf(v, __shfl_xor(v, 2));
      v = fmaxf(v, __shfl_xor(v, 4));
      v = fmaxf(v, __shfl_xor(v, 8));
      rm[mi][rg] = v;
    }

  float* rmaxs = (float*)lb;   // reuse staging LDS: [2 wc][128 rows]
  __syncthreads();
  if (lr == 0) {
    #pragma unroll
    for (int mi = 0; mi < 4; ++mi)
      #pragma unroll
      for (int rg = 0; rg < 4; ++rg)
        rmaxs[wc * 128 + wr * 64 + mi * 16 + q * 4 + rg] = rm[mi][rg];
  }
  __syncthreads();
  if (tid < 128) {
    float v = fmaxf(rmaxs[tid], rmaxs[128 + tid]);
    partial[(size_t)(m0 + tid) * NGROUPS + nc] = v;
  }
}

// K4: out[r] = 1 - max over 32 partials. 2 rows per 64-thread block.
__global__ void reduce_max(const float* __restrict__ partial, float* __restrict__ out) {
  const int r = blockIdx.x * 2 + (threadIdx.x >> 5);
  const int c = threadIdx.x & 31;
  float m = partial[(size_t)r * NGROUPS + c];
  #pragma unroll
  for (int s = 1; s < 32; s <<= 1) m = fmaxf(m, __shfl_xor(m, s));
  if (c == 0) out[r] = 1.0f - m;
}

extern "C" void kernel_launch(void* const* d_in, const int* in_sizes, int n_in,
                              void* d_out, int out_size, void* d_ws, size_t ws_size,
                              hipStream_t stream) {
  const float* x   = (const float*)d_in[0];   // [2048, 2048]
  const float* R   = (const float*)d_in[1];   // [2048, 256]
  const float* buf = (const float*)d_in[2];   // [131072, 256]
  float* out = (float*)d_out;                  // [2048]

  char* ws = (char*)d_ws;
  // ws layout: rt 1MB | buf_bf 64MB | sx_bf 1MB | partial 256KB
  unsigned short* rt   = (unsigned short*)(ws);
  unsigned short* bufb = (unsigned short*)(ws + (1ull << 20));
  unsigned short* sxb  = (unsigned short*)(ws + (1ull << 20) + (64ull << 20));
  float*          part = (float*)         (ws + (1ull << 20) + (64ull << 20) + (1ull << 20));

  transpose_R<<<dim3((DIM * SKDIM) / 256), dim3(256), 0, stream>>>(R, rt);
  sketch_conv<<<dim3(2080), dim3(256), 0, stream>>>(x, rt, sxb, buf, bufb);
  gemm_sim<<<dim3(512), dim3(256), 0, stream>>>(sxb, bufb, part);
  reduce_max<<<dim3(BROWS / 2), dim3(64), 0, stream>>>(part, out);
}